// Round 1
// 1628.744 us; speedup vs baseline: 1.1645x; 1.1645x over previous
//
#include <hip/hip_runtime.h>
#include <stdint.h>

typedef unsigned short u16;
typedef __attribute__((ext_vector_type(8))) short bfrag8;   // 8 bf16 (4 VGPRs)
typedef __attribute__((ext_vector_type(4))) float f32x4;

#define DEV static __device__ __forceinline__

DEV u16 f2bf(float f) {                    // RNE f32 -> bf16 (finite inputs)
  uint32_t u = __float_as_uint(f);
  u += 0x7fffu + ((u >> 16) & 1u);
  return (u16)(u >> 16);
}

// async global->LDS, 16B per lane. LDS dest is wave-uniform base; HW adds lane*16.
DEV void async_lds16(const void* g, void* l) {
  const __attribute__((address_space(1))) uint32_t* gp =
      (const __attribute__((address_space(1))) uint32_t*)(uintptr_t)g;
  __attribute__((address_space(3))) uint32_t* lp =
      (__attribute__((address_space(3))) uint32_t*)(uint32_t)(uintptr_t)l;  // low 32 bits = LDS offset
  __builtin_amdgcn_global_load_lds(gp, lp, 16, 0, 0);
}

// shift table {-4,1,2,-1,0,3,-2,-3,4} packed as nibbles (+4), idx=(i%3)*3+(j%3)
DEV int shift_of(int n) {
  int i = n / 7, j = n - i * 7;
  int idx = (i % 3) * 3 + (j % 3);
  return (int)((0x812743650ull >> (4 * idx)) & 15ull) - 4;
}

#define FENCE asm volatile("" ::: "memory")

// ---------------- f32 -> bf16 cast ----------------
__global__ void k_f32_to_bf16(const float* __restrict__ src, u16* __restrict__ dst, int n4) {
  int i = blockIdx.x * blockDim.x + threadIdx.x;
  const int stride = gridDim.x * blockDim.x;
  for (; i < n4; i += stride) {
    float4 v = ((const float4*)src)[i];
    union { u16 h[4]; uint2 u; } o;
    o.h[0] = f2bf(v.x); o.h[1] = f2bf(v.y); o.h[2] = f2bf(v.z); o.h[3] = f2bf(v.w);
    ((uint2*)dst)[i] = o.u;
  }
}

// ---------------- bias pre-gather: bias[h][n][m] ----------------
__global__ void k_bias_pre(const float* __restrict__ tab, const int* __restrict__ ridx,
                           float* __restrict__ bp) {
  int nm = blockIdx.x * blockDim.x + threadIdx.x;
  if (nm < 2401) {
    int idx = ridx[nm];
#pragma unroll
    for (int h = 0; h < 16; ++h) bp[h * 2401 + nm] = tab[idx * 16 + h];
  }
}

// ---------------- NT bf16 GEMM, 256x256 8-phase (m201 template) ----------------
// C[M,N] = A[M,K] * B[N,K]^T (+bias). 8 waves (2M x 4N), BK=64, 128 KiB LDS dbuf,
// T2 XOR-swizzle both-sides, counted vmcnt(4) at phases 4/8, setprio around MFMA,
// XCD-contiguous block remap with bn-fastest decode (A panel reuse in per-XCD L2).
// Requires: M%256==0, N%256==0, K%128==0, gridDim.x == (M/256)*(N/256) % 8 == 0.
template <int OUT_F32, int NBN>
__global__ __launch_bounds__(512, 2) void k_gemm8(const u16* __restrict__ A,
                                                  const u16* __restrict__ B,
                                                  void* __restrict__ Cp,
                                                  const float* __restrict__ bias,
                                                  int M, int N, int K, int nwg) {
  (void)M;
  // LDS: buf b at b*32768 (u16); within buf: A [256][64] at 0, B [256][64] at 16384.
  // Swizzle: logical (row,c) stored at u16 index row*64 + (c ^ ((row&7)<<3)).
  __shared__ __align__(16) u16 lds[65536];  // 128 KiB
  const int tid = threadIdx.x;
  const int wave = tid >> 6, lane = tid & 63;
  const int quad = lane >> 4, l16 = lane & 15;
  const int wm = wave >> 2, wn = wave & 3;

  // XCD-bijective remap (nwg % 8 == 0), bn-fastest decode.
  const int cpx = nwg >> 3;
  const int wg = ((int)blockIdx.x & 7) * cpx + ((int)blockIdx.x >> 3);
  const int bn = wg % NBN, bm = wg / NBN;

  // staging addresses: thread covers physical u16 [tid*8, tid*8+8) per issue,
  // source col pre-inverse-swizzled so linear LDS dest holds swizzled layout.
  const int r8 = tid >> 3;                           // 0..63 row within issue
  const int cu = (((tid & 7) ^ (r8 & 7)) << 3);      // logical col (u16), pre-swizzled
  const u16* gA = A + (long)(bm * 256 + r8) * K + cu;
  const u16* gB = B + (long)(bn * 256 + r8) * K + cu;
  const long istep = (long)64 * K;                   // +64 rows (2nd issue)
  const long hstep = (long)128 * K;                  // +128 rows (half)

#define STAGE_A(t, h) do { const u16* g_ = gA + (h) * hstep + (t) * 64; \
    u16* l_ = &lds[(((t) & 1) << 15) + ((h) << 13) + (wave << 9)]; \
    async_lds16(g_, l_); async_lds16(g_ + istep, l_ + 4096); } while (0)
#define STAGE_B(t, h) do { const u16* g_ = gB + (h) * hstep + (t) * 64; \
    u16* l_ = &lds[(((t) & 1) << 15) + 16384 + ((h) << 13) + (wave << 9)]; \
    async_lds16(g_, l_); async_lds16(g_ + istep, l_ + 4096); } while (0)

  // fragment read addressing (swizzled): col = (ksub*32 + quad*8) ^ ((l16&7)<<3)
  const int c0 = (quad << 3) ^ ((l16 & 7) << 3);
  const int arow = (wm << 6) + l16;   // A row base within 256: + (mh<<7) + (a<<4)
  const int brow = (wn << 5) + l16;   // B row base within 256: + (nh<<7) + (b<<4)

#define LOADS_A(t, mh) do { const int cb_ = ((t) & 1) << 15; \
    _Pragma("unroll") for (int a_ = 0; a_ < 4; ++a_) { \
      const int ro_ = cb_ + ((((mh) << 7) + (a_ << 4) + arow) << 6); \
      fa[a_ * 2 + 0] = *(const bfrag8*)&lds[ro_ + c0]; \
      fa[a_ * 2 + 1] = *(const bfrag8*)&lds[ro_ + (c0 ^ 32)]; } } while (0)
#define LOADS_B(t, nh) do { const int cb_ = (((t) & 1) << 15) + 16384; \
    _Pragma("unroll") for (int b_ = 0; b_ < 2; ++b_) { \
      const int ro_ = cb_ + ((((nh) << 7) + (b_ << 4) + brow) << 6); \
      fb[((nh) * 2 + b_) * 2 + 0] = *(const bfrag8*)&lds[ro_ + c0]; \
      fb[((nh) * 2 + b_) * 2 + 1] = *(const bfrag8*)&lds[ro_ + (c0 ^ 32)]; } } while (0)
#define MFMA8(mh, nh) do { \
    __builtin_amdgcn_s_setprio(1); \
    _Pragma("unroll") for (int a_ = 0; a_ < 4; ++a_) \
    _Pragma("unroll") for (int b_ = 0; b_ < 2; ++b_) { \
      f32x4& c_ = acc[(mh) * 4 + a_][(nh) * 2 + b_]; \
      c_ = __builtin_amdgcn_mfma_f32_16x16x32_bf16(fa[a_ * 2 + 0], fb[((nh) * 2 + b_) * 2 + 0], c_, 0, 0, 0); \
      c_ = __builtin_amdgcn_mfma_f32_16x16x32_bf16(fa[a_ * 2 + 1], fb[((nh) * 2 + b_) * 2 + 1], c_, 0, 0, 0); } \
    __builtin_amdgcn_s_setprio(0); } while (0)
#define BAR do { FENCE; __builtin_amdgcn_s_barrier(); FENCE; } while (0)

  f32x4 acc[8][4] = {};
  bfrag8 fa[8], fb[8];

  // prologue: t0 fully + t1 halves {A0,B0}; wait leaves t1's 2 halves in flight.
  STAGE_A(0, 0); STAGE_B(0, 0); STAGE_A(0, 1); STAGE_B(0, 1);
  STAGE_A(1, 0); STAGE_B(1, 0);
  asm volatile("s_waitcnt vmcnt(4)" ::: "memory");
  __builtin_amdgcn_s_barrier();
  FENCE;

  const int nIter = K >> 7;           // 2 K-tiles (BK=64) per iteration
  for (int I = 0; I < nIter; ++I) {
    const int t0 = I * 2, t1 = t0 + 1, t2 = t0 + 2, t3 = t0 + 3;
    const bool more = (I + 1) < nIter;
    // p1: compute t0 (mh0,nh0); stage t1.Ah1 (its region freed at p7 of I-1)
    LOADS_A(t0, 0); LOADS_B(t0, 0);
    STAGE_A(t1, 1);
    BAR; MFMA8(0, 0); BAR;
    // p2: (mh0,nh1); stage t1.Bh1 (freed p6 of I-1)
    LOADS_B(t0, 1);
    STAGE_B(t1, 1);
    BAR; MFMA8(0, 1); BAR;
    // p3: (mh1,nh0); stage t2.Ah0 (freed p1)
    LOADS_A(t0, 1);
    if (more) STAGE_A(t2, 0);
    BAR; MFMA8(1, 0); BAR;
    // p4: (mh1,nh1); stage t2.Bh0 (freed p1); W4 retires all of t1's staging
    if (more) { STAGE_B(t2, 0); asm volatile("s_waitcnt vmcnt(4)" ::: "memory"); }
    else      { asm volatile("s_waitcnt vmcnt(0)" ::: "memory"); }
    BAR; MFMA8(1, 1); BAR;
    // p5: compute t1 (mh0,nh0); stage t2.Ah1 (freed p3)
    LOADS_A(t1, 0); LOADS_B(t1, 0);
    if (more) STAGE_A(t2, 1);
    BAR; MFMA8(0, 0); BAR;
    // p6: (mh0,nh1); stage t2.Bh1 (freed p2)
    LOADS_B(t1, 1);
    if (more) STAGE_B(t2, 1);
    BAR; MFMA8(0, 1); BAR;
    // p7: (mh1,nh0); stage t3.Ah0 (freed p5)
    LOADS_A(t1, 1);
    if (more) STAGE_A(t3, 0);
    BAR; MFMA8(1, 0); BAR;
    // p8: (mh1,nh1); stage t3.Bh0 (freed p5); W8 retires all of t2's staging
    if (more) { STAGE_B(t3, 0); asm volatile("s_waitcnt vmcnt(4)" ::: "memory"); }
    BAR; MFMA8(1, 1); BAR;
  }

  // epilogue: per-wave 128x64; C/D map col=l16, row=quad*4+i (verified mapping)
#pragma unroll
  for (int g = 0; g < 4; ++g) {
    const int col = (bn << 8) + ((g >> 1) << 7) + (wn << 5) + ((g & 1) << 4) + l16;
    const float bv = OUT_F32 ? bias[col] : 0.0f;
#pragma unroll
    for (int f = 0; f < 8; ++f) {
      const long rb = (long)(bm << 8) + ((f >> 2) << 7) + (wm << 6) + ((f & 3) << 4) + (quad << 2);
#pragma unroll
      for (int i = 0; i < 4; ++i) {
        const float v = acc[f][g][i] + bv;
        const long off = (rb + i) * N + col;
        if (OUT_F32) ((float*)Cp)[off] = v;
        else         ((u16*)Cp)[off] = f2bf(v);
      }
    }
  }
#undef STAGE_A
#undef STAGE_B
#undef LOADS_A
#undef LOADS_B
#undef MFMA8
#undef BAR
}

// ---------------- fused shifted window attention ----------------
// One wave per (bflat, h) unit; 4 units per block. qkv: [M,1536] bf16 (q|k|v per head).
// out_pre: [M,512] bf16, inverse shift folded into store.
__global__ __launch_bounds__(256) void k_attn(const u16* __restrict__ qkv,
                                              const float* __restrict__ bias_pre,
                                              u16* __restrict__ out_pre) {
  __shared__ __align__(16) u16 smem[4][6144];  // per wave: qs[64][32] ks[64][32] vt[32][64]; ps aliases qs+ks
  const int tid = threadIdx.x;
  const int wave = tid >> 6, lane = tid & 63;
  const int quad = lane >> 4, l16 = lane & 15;

  const int unit = (blockIdx.x << 2) + wave;  // 0..65535
  const int h = unit & 15;
  const int bflat = unit >> 4;
  const int w = bflat & 63;
  const int t = (bflat >> 6) & 15;
  const int b = bflat >> 10;

  u16* qs = &smem[wave][0];
  u16* ks = &smem[wave][2048];
  u16* vt = &smem[wave][4096];
  u16* ps = &smem[wave][0];     // [64][64] over dead q/k after QK^T

  // zero vt pad (cols 48..63; col 48 rewritten by staging) — NaN safety for PV
#pragma unroll
  for (int it = 0; it < 8; ++it) {
    int idx = it * 64 + lane;
    vt[(idx >> 4) * 64 + 48 + (idx & 15)] = 0;
  }

  const int r_off = lane >> 2;
  const int ch8 = (lane & 3) << 3;

  // q,k: shifted gather straight into LDS (64 rows; rows>=49 clamp to 48 -> finite garbage)
#pragma unroll
  for (int pass = 0; pass < 4; ++pass) {
    int r = pass * 16 + r_off;
    int rc = r > 48 ? 48 : r;
    int ts = (t - shift_of(rc) + 16) & 15;
    long row = ((long)((b * 16 + ts) * 64 + w)) * 49 + rc;
    const u16* gq = qkv + row * 1536 + h * 32 + ch8;
    async_lds16(gq, qs + pass * 512);
    async_lds16(gq + 512, ks + pass * 512);
  }
  // v: shifted gather + transpose into vt[cc][m]
#pragma unroll
  for (int pass = 0; pass < 4; ++pass) {
    int r = pass * 16 + r_off;
    if (r < 49) {
      int ts = (t - shift_of(r) + 16) & 15;
      long row = ((long)((b * 16 + ts) * 64 + w)) * 49 + r;
      uint4 d = *(const uint4*)(qkv + row * 1536 + 1024 + h * 32 + ch8);
      const u16* pd = (const u16*)&d;
#pragma unroll
      for (int jj = 0; jj < 8; ++jj) vt[(ch8 + jj) * 64 + r] = pd[jj];
    }
  }

  __builtin_amdgcn_s_waitcnt(0);       // drain LDS-DMA + ds writes (wave-private unit, no barrier)
  __builtin_amdgcn_sched_barrier(0);

  // S = Q K^T  (A/B frags: rows x 32k contiguous; C/D: col=l16, row=quad*4+i)
  bfrag8 aq[4], bk[4];
#pragma unroll
  for (int tn = 0; tn < 4; ++tn) aq[tn] = *(const bfrag8*)&qs[(tn * 16 + l16) * 32 + quad * 8];
#pragma unroll
  for (int tm = 0; tm < 4; ++tm) bk[tm] = *(const bfrag8*)&ks[(tm * 16 + l16) * 32 + quad * 8];

  f32x4 s[4][4] = {};
#pragma unroll
  for (int tn = 0; tn < 4; ++tn)
#pragma unroll
    for (int tm = 0; tm < 4; ++tm)
      s[tn][tm] = __builtin_amdgcn_mfma_f32_16x16x32_bf16(aq[tn], bk[tm], s[tn][tm], 0, 0, 0);

  const float scale = 0.17677669529663687f;  // 32^-0.5
#pragma unroll
  for (int tm = 0; tm < 4; ++tm) {
    const int col = tm * 16 + l16;
    const bool valid = col < 49;
    const float* bp = bias_pre + h * 2401 + col;
#pragma unroll
    for (int tn = 0; tn < 4; ++tn)
#pragma unroll
      for (int i = 0; i < 4; ++i) {
        const int row = tn * 16 + quad * 4 + i;
        const int rowc = row > 48 ? 48 : row;
        s[tn][tm][i] = valid ? (s[tn][tm][i] * scale + bp[rowc * 49]) : -1e30f;
      }
  }

  // online row max / exp / sum; P (unnormalized) -> bf16 into ps; 1/l applied at store
  float rinv[4][4];
#pragma unroll
  for (int tn = 0; tn < 4; ++tn) {
#pragma unroll
    for (int i = 0; i < 4; ++i) {
      float m = fmaxf(fmaxf(s[tn][0][i], s[tn][1][i]), fmaxf(s[tn][2][i], s[tn][3][i]));
      m = fmaxf(m, __shfl_xor(m, 1));
      m = fmaxf(m, __shfl_xor(m, 2));
      m = fmaxf(m, __shfl_xor(m, 4));
      m = fmaxf(m, __shfl_xor(m, 8));
      float l = 0.f;
#pragma unroll
      for (int tm = 0; tm < 4; ++tm) {
        float p = __expf(s[tn][tm][i] - m);
        l += p;
        ps[(tn * 16 + quad * 4 + i) * 64 + tm * 16 + l16] = f2bf(p);
      }
      l += __shfl_xor(l, 1);
      l += __shfl_xor(l, 2);
      l += __shfl_xor(l, 4);
      l += __shfl_xor(l, 8);
      rinv[tn][i] = 1.0f / l;
    }
  }

  // O = P V   (A from ps rows; B from vt[cc][m] rows)
  f32x4 o[4][2] = {};
#pragma unroll
  for (int kt = 0; kt < 2; ++kt) {
    bfrag8 ap[4], bv[2];
#pragma unroll
    for (int tn = 0; tn < 4; ++tn)
      ap[tn] = *(const bfrag8*)&ps[(tn * 16 + l16) * 64 + kt * 32 + quad * 8];
#pragma unroll
    for (int ct = 0; ct < 2; ++ct)
      bv[ct] = *(const bfrag8*)&vt[(ct * 16 + l16) * 64 + kt * 32 + quad * 8];
#pragma unroll
    for (int tn = 0; tn < 4; ++tn)
#pragma unroll
      for (int ct = 0; ct < 2; ++ct)
        o[tn][ct] = __builtin_amdgcn_mfma_f32_16x16x32_bf16(ap[tn], bv[ct], o[tn][ct], 0, 0, 0);
  }

  // store with inverse shift (same time map as q gather)
#pragma unroll
  for (int tn = 0; tn < 4; ++tn)
#pragma unroll
    for (int i = 0; i < 4; ++i) {
      const int row = tn * 16 + quad * 4 + i;
      if (row < 49) {
        const int ts = (t - shift_of(row) + 16) & 15;
        const long fd = (long)((b * 16 + ts) * 64 + w);
        const long base = (fd * 49 + row) * 512 + h * 32;
        const float r = rinv[tn][i];
        out_pre[base + l16]      = f2bf(o[tn][0][i] * r);
        out_pre[base + 16 + l16] = f2bf(o[tn][1][i] * r);
      }
    }
}

// ---------------- launch ----------------
extern "C" void kernel_launch(void* const* d_in, const int* in_sizes, int n_in,
                              void* d_out, int out_size, void* d_ws, size_t ws_size,
                              hipStream_t stream) {
  const float* x       = (const float*)d_in[0];
  const float* qkv_w   = (const float*)d_in[1];
  const float* proj_w  = (const float*)d_in[2];
  const float* proj_b  = (const float*)d_in[3];
  const float* rel_tab = (const float*)d_in[4];
  const int*   rel_idx = (const int*)d_in[5];
  // d_in[6]=batch_size(4), d_in[7]=frame_len(16): fixed by setup, hardcoded.

  const long M = 200704;  // 4096*49 = 784*256
  char* ws = (char*)d_ws;
  u16*   x_bf     = (u16*)ws;                                    // M*512 bf16 (reused as attn_out)
  u16*   qkvw_bf  = (u16*)(ws + 205520896);                      // 1536*512
  u16*   projw_bf = (u16*)(ws + 205520896 + 1572864);            // 512*512
  float* bias_pre = (float*)(ws + 205520896 + 1572864 + 524288); // 16*2401 (+slack)
  u16*   qkv_buf  = (u16*)(ws + 205520896 + 1572864 + 524288 + 262144); // M*1536 bf16

  k_f32_to_bf16<<<4096, 256, 0, stream>>>(x, x_bf, (int)(M * 512 / 4));
  k_f32_to_bf16<<<768, 256, 0, stream>>>(qkv_w, qkvw_bf, 1536 * 512 / 4);
  k_f32_to_bf16<<<256, 256, 0, stream>>>(proj_w, projw_bf, 512 * 512 / 4);
  k_bias_pre<<<10, 256, 0, stream>>>(rel_tab, rel_idx, bias_pre);

  // QKV GEMM: 784 x 6 = 4704 tiles (divisible by 8 for XCD remap)
  k_gemm8<0, 6><<<4704, 512, 0, stream>>>(x_bf, qkvw_bf, (void*)qkv_buf, nullptr,
                                          (int)M, 1536, 512, 4704);

  u16* attn_out = x_bf;  // x_bf dead after gemm1
  k_attn<<<16384, 256, 0, stream>>>(qkv_buf, bias_pre, attn_out);

  // proj GEMM: 784 x 2 = 1568 tiles
  k_gemm8<1, 2><<<1568, 512, 0, stream>>>(attn_out, projw_bf, d_out, proj_b,
                                          (int)M, 512, 512, 1568);
}